// Round 13
// baseline (83.663 us; speedup 1.0000x reference)
//
#include <hip/hip_runtime.h>
#include <hip/hip_bf16.h>
#include <math.h>

#define BB 32
#define TT 512
#define SS 128
#define CC 30
#define WW 10
#define DCTX 768
#define DENT 300
#define HH 100
#define EPSF 1e-5f
#define NEGF -1e30f
#define PSTR 320               // proj row stride (bf16), 640 B

typedef __attribute__((ext_vector_type(8))) short bf16x8;
typedef __attribute__((ext_vector_type(4))) float f32x4;

#define NK  (DCTX / 32)        // 24 K-steps
#define NCT 20                 // col-tiles of 16 (320 cols >= 300)

// ---- DPP wave64 reduction: 6 VALU ops + readlane, NO DS traffic ----------
template<int C, int M>
__device__ __forceinline__ float dppadd(float x) {
    union { float f; int i; } u, r;
    u.f = x;
    r.i = __builtin_amdgcn_update_dpp(0, u.i, C, M, 0xf, true);
    return x + r.f;
}
__device__ __forceinline__ float wave_red(float x) {
    x = dppadd<0x111, 0xf>(x);   // row_shr:1
    x = dppadd<0x112, 0xf>(x);   // row_shr:2
    x = dppadd<0x114, 0xf>(x);   // row_shr:4
    x = dppadd<0x118, 0xf>(x);   // row_shr:8
    x = dppadd<0x142, 0xa>(x);   // row_bcast:15 -> rows 1,3
    x = dppadd<0x143, 0xc>(x);   // row_bcast:31 -> rows 2,3
    union { float f; int i; } u; u.f = x;
    u.i = __builtin_amdgcn_readlane(u.i, 63);
    return u.f;
}

// ---- async global->LDS DMA, 16 B per lane ---------------------------------
__device__ __forceinline__ void dma16(const float* g, float* l) {
    __builtin_amdgcn_global_load_lds(
        (const __attribute__((address_space(1))) void*)g,
        (__attribute__((address_space(3))) void*)l, 16, 0, 0);
}

__device__ __forceinline__ ushort f2bf(float f) {
    __hip_bfloat16 h = __float2bfloat16(f);
    return *reinterpret_cast<ushort*>(&h);
}
__device__ __forceinline__ float bf2f1(short s) {
    union { unsigned u; float f; } t;
    t.u = ((unsigned)(unsigned short)s) << 16;
    return t.f;
}
__device__ __forceinline__ void bf8_cvt(bf16x8 v, float4& lo, float4& hi) {
    lo.x = bf2f1(v[0]); lo.y = bf2f1(v[1]); lo.z = bf2f1(v[2]); lo.w = bf2f1(v[3]);
    hi.x = bf2f1(v[4]); hi.y = bf2f1(v[5]); hi.z = bf2f1(v[6]); hi.w = bf2f1(v[7]);
}

__device__ __forceinline__ float dot4(float4 a, float4 b) {
    return a.x*b.x + a.y*b.y + a.z*b.z + a.w*b.w;
}
__device__ __forceinline__ float hadd8(float4 a, float4 b) {
    return a.x+a.y+a.z+a.w + b.x+b.y+b.z+b.w;
}
__device__ __forceinline__ ushort4 cvt4(float4 v) {
    ushort4 h; h.x = f2bf(v.x); h.y = f2bf(v.y); h.z = f2bf(v.z); h.w = f2bf(v.w);
    return h;
}

// ---------------------------------------------------------------------------
// K0: proj_W (300x768 f32) -> frag-major bf16 (zero-padded cols 300..319).
// ---------------------------------------------------------------------------
__global__ __launch_bounds__(256) void wpre_kernel(
    const float* __restrict__ Wt, ushort* __restrict__ wpre)
{
    const int g = blockIdx.x * 256 + threadIdx.x;
    const int l = g & 63;
    const int t = (g >> 6) % NK;
    const int ct = g / (NK * 64);
    const int col = ct * 16 + (l & 15);
    const int k = t * 32 + (l >> 4) * 8;
    ushort4 h0 = {0, 0, 0, 0}, h1 = {0, 0, 0, 0};
    if (col < DENT) {
        h0 = cvt4(*(const float4*)(Wt + (size_t)col * DCTX + k));
        h1 = cvt4(*(const float4*)(Wt + (size_t)col * DCTX + k + 4));
    }
    *(ushort4*)(wpre + (size_t)g * 8)     = h0;
    *(ushort4*)(wpre + (size_t)g * 8 + 4) = h1;
}

// ---------------------------------------------------------------------------
// K1: proj(bf16, stride 320) = ctx @ proj_W.T + proj_b -- hybrid MFMA GEMM
// (R6/R9 core, proven). Cols 300..319 written as exact zeros.
// ---------------------------------------------------------------------------
#define GBM 64
#define LDA 40

__global__ __launch_bounds__(512) void gemm_proj_mfma(
    const float*  __restrict__ A,     // (16384, 768)
    const ushort* __restrict__ wpre,  // frag-major bf16 W
    const float*  __restrict__ bias,  // (300)
    ushort* __restrict__ out)         // (16384, PSTR) bf16
{
    __shared__ ushort Al[2][GBM * LDA];
    const int tid = threadIdx.x;
    const int lane = tid & 63;
    const int wv = tid >> 6;
    const int wm = wv >> 2;
    const int wn = wv & 3;
    const int m0 = blockIdx.x * GBM;
    const int ar = tid >> 3;
    const int ak = (tid & 7) * 4;
    const int lr = lane & 15;
    const int kq = (lane >> 4) * 8;

    const float* aP = A + (size_t)(m0 + ar) * DCTX + ak;
    const ushort* bp = wpre + (size_t)wn * 5 * NK * 512 + (size_t)lane * 8;

    f32x4 acc[2][5];
    #pragma unroll
    for (int i = 0; i < 2; ++i)
        #pragma unroll
        for (int j = 0; j < 5; ++j)
            acc[i][j] = (f32x4){0.f, 0.f, 0.f, 0.f};

    bf16x8 cb[5], nb[5];
    #pragma unroll
    for (int j = 0; j < 5; ++j)
        cb[j] = *(const bf16x8*)(bp + (size_t)j * NK * 512);

#define STOREA(BUF, v_) (*(ushort4*)&Al[BUF][ar * LDA + ak] = cvt4(v_))

#define COMPUTE(BUF) do {                                                      \
        bf16x8 af_[2];                                                         \
        _Pragma("unroll")                                                      \
        for (int i_ = 0; i_ < 2; ++i_)                                         \
            af_[i_] = *(const bf16x8*)&Al[BUF][(wm*32 + i_*16 + lr)*LDA + kq]; \
        _Pragma("unroll")                                                      \
        for (int j_ = 0; j_ < 5; ++j_)                                         \
            acc[0][j_] = __builtin_amdgcn_mfma_f32_16x16x32_bf16(              \
                af_[0], cb[j_], acc[0][j_], 0, 0, 0);                          \
        _Pragma("unroll")                                                      \
        for (int j_ = 0; j_ < 5; ++j_)                                         \
            acc[1][j_] = __builtin_amdgcn_mfma_f32_16x16x32_bf16(              \
                af_[1], cb[j_], acc[1][j_], 0, 0, 0);                          \
    } while (0)

    float4 avA = *(const float4*)(aP);
    float4 avB = *(const float4*)(aP + 32);
    STOREA(0, avA);
    __syncthreads();

    #pragma unroll 1
    for (int kk = 0; kk < NK; kk += 2) {
        #pragma unroll
        for (int j = 0; j < 5; ++j)
            nb[j] = *(const bf16x8*)(bp + ((size_t)j * NK + kk + 1) * 512);
        if (kk + 2 < NK) avA = *(const float4*)(aP + (kk + 2) * 32);
        COMPUTE(0);
        STOREA(1, avB);
        __syncthreads();
        #pragma unroll
        for (int j = 0; j < 5; ++j) cb[j] = nb[j];
        if (kk + 2 < NK) {
            #pragma unroll
            for (int j = 0; j < 5; ++j)
                nb[j] = *(const bf16x8*)(bp + ((size_t)j * NK + kk + 2) * 512);
            avB = *(const float4*)(aP + (kk + 3) * 32);
        }
        COMPUTE(1);
        if (kk + 2 < NK) STOREA(0, avA);
        __syncthreads();
        #pragma unroll
        for (int j = 0; j < 5; ++j) cb[j] = nb[j];
    }

    const int lq = lane >> 4;
    #pragma unroll
    for (int j = 0; j < 5; ++j) {
        int col = wn * 80 + j * 16 + lr;
        float bv = (col < DENT) ? bias[col] : 0.f;   // col>=300: acc=0, bv=0
        #pragma unroll
        for (int i = 0; i < 2; ++i)
            #pragma unroll
            for (int r = 0; r < 4; ++r) {
                int row = m0 + wm * 32 + i * 16 + lq * 4 + r;
                out[(size_t)row * PSTR + col] = f2bf(acc[i][j][r] + bv);
            }
    }
}

// ---------------------------------------------------------------------------
// K2: span extraction + LN from bf16 proj. 4 spans/block, one wave each.
// Lane layout: lanes 0..37 own elems dl=lane*8..+7 (one bf16x8 per row).
// Rows kept as bf16x8 in registers (40 VGPR vs 80 f32).
// ---------------------------------------------------------------------------
__global__ __launch_bounds__(256) void span_kernel(
    const ushort* __restrict__ proj,    // (B*T, PSTR) bf16
    const int*    __restrict__ spans,   // (B*S, 2)
    const float*  __restrict__ attn_W,  // (300)
    const float*  __restrict__ attn_b,  // (1)
    const float*  __restrict__ ln_g,
    const float*  __restrict__ ln_b,
    const float*  __restrict__ kg_g,
    const float*  __restrict__ kg_b,
    float* __restrict__ srg_out,        // (B*S, 300)
    float* __restrict__ sgsb)           // (B*S, 2)
{
    const int bs = blockIdx.x * 4 + (threadIdx.x >> 6);
    const int b = bs >> 7;   // SS = 128
    const int lane = threadIdx.x & 63;
    const int start = spans[bs * 2 + 0];
    const int end   = spans[bs * 2 + 1];
    const int width = end - start;
    const bool L   = lane < 38;               // active element lanes
    const int  dl  = (L ? lane : 37) * 8;     // 0..296
    const bool g2  = dl + 4 < DENT;           // second float4 valid (dl<296)
    const float4 z = make_float4(0.f, 0.f, 0.f, 0.f);

    float4 w0 = L  ? *(const float4*)(attn_W + dl)     : z;
    float4 w1 = (L && g2) ? *(const float4*)(attn_W + dl + 4) : z;

    bf16x8 rowv[WW];
    float slog[WW];
    bool vld[WW];
    #pragma unroll
    for (int w = 0; w < WW; ++w) {
        int idx = start + w;
        vld[w] = (w <= width) && (idx >= 0) && (idx < TT);
        const ushort* pr = proj + (size_t)(b * TT + (vld[w] ? idx : 0)) * PSTR;
        rowv[w] = *(const bf16x8*)(pr + dl);
        float4 plo, phi; bf8_cvt(rowv[w], plo, phi);
        slog[w] = dot4(plo, w0) + dot4(phi, w1);   // w0/w1 zeroed for !L
    }
    const float ab = attn_b[0];
    #pragma unroll
    for (int w = 0; w < WW; ++w) {
        float r = wave_red(slog[w]);
        slog[w] = vld[w] ? r + ab : NEGF;
    }
    float m = slog[0];
    #pragma unroll
    for (int w = 1; w < WW; ++w) m = fmaxf(m, slog[w]);
    float den = 0.f;
    float aw[WW];
    #pragma unroll
    for (int w = 0; w < WW; ++w) { aw[w] = expf(slog[w] - m); den += aw[w]; }
    const float inv = 1.f / den;
    const float msk = (start > -1) ? inv : 0.f;

    float4 acc0 = z, acc1 = z;
    #pragma unroll
    for (int w = 0; w < WW; ++w) {
        float4 plo, phi; bf8_cvt(rowv[w], plo, phi);
        float c = aw[w] * msk;
        acc0.x = fmaf(c, plo.x, acc0.x); acc0.y = fmaf(c, plo.y, acc0.y);
        acc0.z = fmaf(c, plo.z, acc0.z); acc0.w = fmaf(c, plo.w, acc0.w);
        acc1.x = fmaf(c, phi.x, acc1.x); acc1.y = fmaf(c, phi.y, acc1.y);
        acc1.z = fmaf(c, phi.z, acc1.z); acc1.w = fmaf(c, phi.w, acc1.w);
    }
    if (!L) { acc0 = z; acc1 = z; }           // dedupe lane 38..63 copies
    // phi for lane 37 covers cols 300..303 = exact zeros -> safe in sums
    float s1 = wave_red(hadd8(acc0, acc1));
    float s2 = wave_red(dot4(acc0, acc0) + dot4(acc1, acc1));
    const float mu = s1 * (1.f / DENT);
    const float rstd = rsqrtf(s2 * (1.f / DENT) - mu * mu + EPSF);

    float4 lg0 = L ? *(const float4*)(ln_g + dl) : z;
    float4 lb0 = L ? *(const float4*)(ln_b + dl) : z;
    float4 gg0 = L ? *(const float4*)(kg_g + dl) : z;
    float4 gb0 = L ? *(const float4*)(kg_b + dl) : z;
    float4 lg1 = (L && g2) ? *(const float4*)(ln_g + dl + 4) : z;
    float4 lb1 = (L && g2) ? *(const float4*)(ln_b + dl + 4) : z;
    float4 gg1 = (L && g2) ? *(const float4*)(kg_g + dl + 4) : z;
    float4 gb1 = (L && g2) ? *(const float4*)(kg_b + dl + 4) : z;

    float4 val0, val1;
    val0.x = fmaf((acc0.x - mu) * rstd, lg0.x, lb0.x);
    val0.y = fmaf((acc0.y - mu) * rstd, lg0.y, lb0.y);
    val0.z = fmaf((acc0.z - mu) * rstd, lg0.z, lb0.z);
    val0.w = fmaf((acc0.w - mu) * rstd, lg0.w, lb0.w);
    val1.x = fmaf((acc1.x - mu) * rstd, lg1.x, lb1.x);
    val1.y = fmaf((acc1.y - mu) * rstd, lg1.y, lb1.y);
    val1.z = fmaf((acc1.z - mu) * rstd, lg1.z, lb1.z);
    val1.w = fmaf((acc1.w - mu) * rstd, lg1.w, lb1.w);
    if (!L) { val0 = z; val1 = z; }
    float4 vg0 = make_float4(val0.x*gg0.x, val0.y*gg0.y, val0.z*gg0.z, val0.w*gg0.w);
    float4 vg1 = make_float4(val1.x*gg1.x, val1.y*gg1.y, val1.z*gg1.z, val1.w*gg1.w);

    float* so = srg_out + (size_t)bs * DENT;
    if (L)        *(float4*)(so + dl)     = vg0;
    if (L && g2)  *(float4*)(so + dl + 4) = vg1;

    float pg = wave_red(hadd8(vg0, vg1));
    float pb = wave_red(dot4(val0, gb0) + dot4(val1, gb1));
    if (lane == 0) { sgsb[bs * 2 + 0] = pg; sgsb[bs * 2 + 1] = pb; }
}

// ---------------------------------------------------------------------------
// K3: fused scores + softmax + weighted sum (R12: DMA-to-LDS, low VGPR).
// priors hoisted out of the reduce loop.
// ---------------------------------------------------------------------------
__global__ __launch_bounds__(512, 8) void final_fused(
    const float* __restrict__ srg,      // (B*S, 300)
    const float* __restrict__ sgsb,     // (B*S, 2)
    const int*   __restrict__ cand,     // (B*S*30)
    const float* __restrict__ priors,   // (B*S*30)
    const float* __restrict__ table,    // (V, 300)
    const float* __restrict__ W1,       // (100,2)
    const float* __restrict__ b1,       // (100)
    const float* __restrict__ W2,       // (100)
    const float* __restrict__ b2,       // (1)
    const float* __restrict__ kg_g,
    const float* __restrict__ kg_b,
    float* __restrict__ out_link,       // (B*S*30)
    float* __restrict__ out_w)          // (B*S, 300)
{
    __shared__ float rows[CC][DENT];
    __shared__ float smu[CC], srs[CC], ssc[CC], sexp[CC];
    const int bs = blockIdx.x;
    const int tid = threadIdx.x;
    const int lane = tid & 63;
    const int wv = tid >> 6;
    const bool lo = lane < 11;
    const float4 z = make_float4(0.f, 0.f, 0.f, 0.f);

    int es[4] = {0, 0, 0, 0};
    float prv[4] = {0.f, 0.f, 0.f, 0.f};
    #pragma unroll
    for (int k = 0; k < 4; ++k) {
        int c = wv + k * 8;
        if (c < CC) {
            int e = cand[bs * CC + c];
            es[k] = e;
            prv[k] = priors[bs * CC + c];
            const float* src = table + (size_t)e * DENT;
            dma16(src + lane * 4, &rows[c][0]);
            if (lo) dma16(src + 256 + lane * 4, &rows[c][256]);
        }
    }

    const float4* sg4 = (const float4*)(srg + (size_t)bs * DENT);
    float4 g0 = sg4[lane];
    float4 g1 = lo ? sg4[64 + lane] : z;
    const float SG = sgsb[bs * 2 + 0];
    const float SB = sgsb[bs * 2 + 1];
    const float W1a0 = W1[2 * lane], W1b0 = W1[2 * lane + 1];
    const float B10 = b1[lane], W20 = W2[lane];
    float W1a1 = 0.f, W1b1 = 0.f, B11 = 0.f, W21 = 0.f;
    if (lane < HH - 64) {
        int j = lane + 64;
        W1a1 = W1[2 * j]; W1b1 = W1[2 * j + 1]; B11 = b1[j]; W21 = W2[j];
    }
    const float b2v = b2[0];
    const float isd = rsqrtf((float)DENT);

    __syncthreads();   // drains DMA

    #pragma unroll
    for (int k = 0; k < 4; ++k) {
        int c = wv + k * 8;
        if (c < CC) {
            float4 xa = *(const float4*)&rows[c][lane * 4];
            float4 xb = lo ? *(const float4*)&rows[c][256 + lane * 4] : z;
            float s1 = wave_red(hadd8(xa, xb));
            float s2 = wave_red(dot4(xa, xa) + dot4(xb, xb));
            float s3 = wave_red(dot4(g0, xa) + dot4(g1, xb));
            float mu = s1 * (1.f / DENT);
            float rstd = rsqrtf(s2 * (1.f / DENT) - mu * mu + EPSF);
            float score = (rstd * (s3 - mu * SG) + SB) * isd;
            float h  = fmaxf(fmaf(W1a0, score, fmaf(W1b0, prv[k], B10)), 0.f);
            float h2 = fmaxf(fmaf(W1a1, score, fmaf(W1b1, prv[k], B11)), 0.f);
            float lp = wave_red(fmaf(W21, h2, W20 * h)) + b2v;
            float link = (es[k] > 0) ? lp : -10000.0f;
            if (lane == 0) {
                smu[c] = mu; srs[c] = rstd; ssc[c] = link;
                out_link[bs * CC + c] = link;
            }
        }
    }
    __syncthreads();

    if (tid < CC) {
        float m = ssc[0];
        #pragma unroll
        for (int c = 1; c < CC; ++c) m = fmaxf(m, ssc[c]);
        sexp[tid] = expf(ssc[tid] - m);
    }
    __syncthreads();

    const int d = tid;
    if (d < DENT) {
        float den = 0.f;
        #pragma unroll
        for (int c = 0; c < CC; ++c) den += sexp[c];
        const float inv = 1.f / den;
        float acc = 0.f, S2 = 0.f, sn = 0.f;
        #pragma unroll
        for (int c = 0; c < CC; ++c) {
            float n = sexp[c] * inv;
            float coef = n * srs[c];
            acc = fmaf(coef, rows[c][d], acc);
            S2 = fmaf(coef, smu[c], S2);
            sn += n;
        }
        out_w[(size_t)bs * DENT + d] = kg_g[d] * (acc - S2) + kg_b[d] * sn;
    }
}

extern "C" void kernel_launch(void* const* d_in, const int* in_sizes, int n_in,
                              void* d_out, int out_size, void* d_ws, size_t ws_size,
                              hipStream_t stream) {
    const float* ctx    = (const float*)d_in[0];
    const int*   spans  = (const int*)d_in[2];
    const int*   cand   = (const int*)d_in[3];
    const float* priors = (const float*)d_in[4];
    const float* table  = (const float*)d_in[6];
    const float* projW  = (const float*)d_in[7];
    const float* projb  = (const float*)d_in[8];
    const float* kg_g   = (const float*)d_in[9];
    const float* kg_b   = (const float*)d_in[10];
    const float* ln_g   = (const float*)d_in[11];
    const float* ln_b   = (const float*)d_in[12];
    const float* attW   = (const float*)d_in[13];
    const float* attb   = (const float*)d_in[14];
    const float* W1     = (const float*)d_in[15];
    const float* b1     = (const float*)d_in[16];
    const float* W2     = (const float*)d_in[17];
    const float* b2     = (const float*)d_in[18];

    ushort* proj = (ushort*)d_ws;                              // (B*T, PSTR) bf16, 10.5 MB
    float*  srg  = (float*)((char*)d_ws + (size_t)BB * TT * PSTR * 2);  // (B*S, 300)
    float*  sgsb = srg + (size_t)BB * SS * DENT;               // (B*S, 2)
    // wpre (492 KB) aliases srg: consumed by gemm before span writes srg.
    ushort* wpre = (ushort*)srg;

    float* out_link = (float*)d_out;                           // (B*S*30)
    float* out_w    = out_link + (size_t)BB * SS * CC;         // (B*S, 300)

    wpre_kernel<<<NCT * NK * 64 / 256, 256, 0, stream>>>(projW, wpre);
    gemm_proj_mfma<<<BB * TT / GBM, 512, 0, stream>>>(ctx, wpre, projb, proj);
    span_kernel<<<BB * SS / 4, 256, 0, stream>>>(proj, spans, attW, attb,
                                                 ln_g, ln_b, kg_g, kg_b, srg, sgsb);
    final_fused<<<BB * SS, 512, 0, stream>>>(srg, sgsb, cand, priors, table,
                                             W1, b1, W2, b2, kg_g, kg_b,
                                             out_link, out_w);
}